// Round 17
// baseline (837.231 us; speedup 1.0000x reference)
//
#include <hip/hip_runtime.h>
#include <stdint.h>
#include <math.h>

// ---------------- problem constants ----------------
#define DM    256      // D_MODEL
#define G3    768      // 3*D
#define TT    512      // T
#define BB    8        // B
#define MM    4096     // B*T
#define OUTD  96       // LATENT+OBJ
#define HH2   512      // 2*D
#define NSTEPS 50
#define NTOT  (MM*OUTD)   // 393216
#define NZTOT ((NSTEPS+1)*NTOT)  // 51 slots: s=0..49 step noise, slot 50 = x0
#define CH    16       // pipeline chunk (timesteps)
#define NCH   (TT/CH)  // 32 chunks
// flag layout: [0..8) f0 L0 steps; [8..16) f1 gi1 chunks(2/ch); [16..24) f2 L1 steps;
// [24..32) f3 gi0 chunks(2/ch); 32 w1done; 33 whh0 done; 34 wih1 done; 35 whh1 done;
// 36 xh96 done; 37 Wc+cbc done; 38 cb1 done
#define F0 0
#define F1 8
#define F2 16
#define F3 24
#define FW1 32
#define FWHH0 33
#define FWIH1 34
#define FWHH1 35
#define FX 36
#define FWC 37
#define FCB1 38

typedef _Float16 f16;
typedef _Float16 f16x2 __attribute__((ext_vector_type(2)));
typedef _Float16 f16x8 __attribute__((ext_vector_type(8)));
typedef float    f32x4 __attribute__((ext_vector_type(4)));

// ---------------- LDS-only barrier ----------------
__device__ __forceinline__ void lds_barrier() {
  asm volatile("s_waitcnt lgkmcnt(0)" ::: "memory");
  __builtin_amdgcn_s_barrier();
}

// ---------------- block-cooperative flag wait (single poller; round-14 proven) ----------------
__device__ __forceinline__ void wait_flag(const uint32_t* f, uint32_t target) {
  if (threadIdx.x == 0) {
    while (__hip_atomic_load(f, __ATOMIC_RELAXED, __HIP_MEMORY_SCOPE_AGENT) < target)
      __builtin_amdgcn_s_sleep(8);
  }
  __builtin_amdgcn_s_barrier();
  __builtin_amdgcn_fence(__ATOMIC_ACQUIRE, "agent");
}

// publish helper: vmcnt drained by __syncthreads, then thread0 release-adds
__device__ __forceinline__ void pub_count(uint32_t* f) {
  __syncthreads();
  if (threadIdx.x == 0)
    __hip_atomic_fetch_add(f, 1u, __ATOMIC_RELEASE, __HIP_MEMORY_SCOPE_AGENT);
}

// ---------------- threefry2x32 (JAX-exact) ----------------
__host__ __device__ inline void tf2x32(uint32_t k0, uint32_t k1,
                                       uint32_t x0, uint32_t x1,
                                       uint32_t& o0, uint32_t& o1)
{
  uint32_t ks2 = k0 ^ k1 ^ 0x1BD11BDAu;
#define ROTL(v,r) (((v)<<(r))|((v)>>(32-(r))))
#define RND(r) { x0 += x1; x1 = ROTL(x1,r); x1 ^= x0; }
  x0 += k0; x1 += k1;
  RND(13) RND(15) RND(26) RND(6)
  x0 += k1;  x1 += ks2 + 1u;
  RND(17) RND(29) RND(16) RND(24)
  x0 += ks2; x1 += k0 + 2u;
  RND(13) RND(15) RND(26) RND(6)
  x0 += k0;  x1 += k1 + 3u;
  RND(17) RND(29) RND(16) RND(24)
  x0 += k1;  x1 += ks2 + 4u;
  RND(13) RND(15) RND(26) RND(6)
  x0 += ks2; x1 += k0 + 5u;
  o0 = x0; o1 = x1;
#undef RND
#undef ROTL
}

// bits -> N(0,1), exactly JAX: uniform in [-0.99999994, 1) then sqrt(2)*erfinv (XLA ErfInv32)
__device__ inline float bits_to_normal(uint32_t bits) {
  float f = __uint_as_float((bits >> 9) | 0x3F800000u) - 1.0f;  // [0,1)
  const float lo = -0.99999994f;
  float u = fmaxf(lo, f * 2.0f + lo);
  float w = -log1pf(-u * u);
  float p;
  if (w < 5.0f) {
    w -= 2.5f;
    p = 2.81022636e-08f;
    p = fmaf(p, w, 3.43273939e-07f);
    p = fmaf(p, w, -3.5233877e-06f);
    p = fmaf(p, w, -4.39150654e-06f);
    p = fmaf(p, w, 0.00021858087f);
    p = fmaf(p, w, -0.00125372503f);
    p = fmaf(p, w, -0.00417768164f);
    p = fmaf(p, w, 0.246640727f);
    p = fmaf(p, w, 1.50140941f);
  } else {
    w = sqrtf(w) - 3.0f;
    p = -0.000200214257f;
    p = fmaf(p, w, 0.000100950558f);
    p = fmaf(p, w, 0.00134934322f);
    p = fmaf(p, w, -0.00367342844f);
    p = fmaf(p, w, 0.00573950773f);
    p = fmaf(p, w, -0.0076224613f);
    p = fmaf(p, w, 0.00943887047f);
    p = fmaf(p, w, 1.00167406f);
    p = fmaf(p, w, 2.83297682f);
  }
  float ei = p * u;
  return 1.41421356f * ei;
}

// partitionable threefry, 32-bit draw: counter=(hi=0, lo=e), bits = o0 ^ o1
__device__ inline float jax_normal_elem(uint32_t k0, uint32_t k1, uint32_t e) {
  uint32_t o0, o1;
  tf2x32(k0, k1, 0u, e, o0, o1);
  return bits_to_normal(o0 ^ o1);
}

// ---------------- small helpers ----------------
__device__ inline float dot2f(f16x2 a, f16x2 b, float c) {
#if __has_builtin(__builtin_amdgcn_fdot2)
  return __builtin_amdgcn_fdot2(a, b, c, false);
#else
  return c + (float)a[0]*(float)b[0] + (float)a[1]*(float)b[1];
#endif
}
__device__ inline float sigmoidf_(float x) { return 1.f / (1.f + __expf(-x)); }
__device__ inline float siluf_(float x)    { return x / (1.f + __expf(-x)); }
// fast tanh via single v_exp: tanh(x) = sign(x) * (1-e)/(1+e), e = exp(-2|x|)
__device__ inline float tanhf_(float x) {
  float e = __expf(-2.f * fabsf(x));
  float t = (1.f - e) / (1.f + e);
  return copysignf(t, x);
}

// fp32 -> OCP e4m3 (RNE). HW cvt when available, else software RNE.
__device__ inline unsigned char f32_to_e4m3(float f) {
#if __has_builtin(__builtin_amdgcn_cvt_pk_fp8_f32)
  int p = __builtin_amdgcn_cvt_pk_fp8_f32(f, f, 0, false);
  return (unsigned char)(p & 0xff);
#else
  uint32_t u = __float_as_uint(f);
  unsigned char s = (unsigned char)((u >> 24) & 0x80);
  float af = fabsf(f);
  if (!(af == af)) return (unsigned char)(s | 0x7f);
  if (af >= 448.f) return (unsigned char)(s | 0x7e);      // sat to max finite
  if (af < 0.0078125f) {                                  // < 2^-7: subnormal range
    int q = (int)rintf(af * 512.f);                       // step 2^-9
    return (unsigned char)(s | q);
  }
  int e; float m = frexpf(af, &e);                        // af = m*2^e, m in [0.5,1)
  int mant = (int)rintf(m * 16.f);                        // 8..16 (RNE)
  if (mant == 16) { mant = 8; e += 1; }
  int E = e - 1 + 7;                                      // biased exponent
  if (E <= 0) { int q = (int)rintf(af * 512.f); return (unsigned char)(s | q); }
  return (unsigned char)(s | (E << 3) | (mant - 8));
#endif
}

// ---------------- diffusion schedule / keys ----------------
struct DiffParams {
  float sra[NSTEPS], coeff[NSTEPS], sb[NSTEPS];
  uint32_t k0[NSTEPS], k1[NSTEPS];
  uint32_t xk0, xk1;
};

// ---------------- GRU scan body v2b + pipeline publish/wait ----------------
template<bool WF, bool WH, bool PUB, bool WAIT>
__device__ __forceinline__ void scan_body(int b, int d,
    const float* __restrict__ gi, const f16* __restrict__ whh,
    const float* __restrict__ bhh,
    float* __restrict__ hf_out, f16* __restrict__ hh_out,
    f16 (*hbuf)[128], uint32_t* pubf, const uint32_t* waitf)
{
  f16x8 wr[16], wz[16], wn[16];
  {
    const f16x8* pr = (const f16x8*)(whh + (size_t)d*DM);
    const f16x8* pz = (const f16x8*)(whh + (size_t)(256+d)*DM);
    const f16x8* pn = (const f16x8*)(whh + (size_t)(512+d)*DM);
    #pragma unroll
    for (int q = 0; q < 16; q++) { wr[q]=pr[q]; wz[q]=pz[q]; wn[q]=pn[q]; }
  }
  if (d < 128) { hbuf[0][d] = (f16)0.f; hbuf[1][d] = (f16)0.f; }
  const float bn = bhh[512 + d];
  float h_old = 0.f;
  __syncthreads();
  const size_t rowbase = (size_t)b * TT;
  if (WAIT) wait_flag(waitf, 2u * 2u);   // chunks 0,1 ready (covers prefetch rows 0..2)
  // 4-slot circular gi prefetch (slots static under x4 unroll)
  float gr[4], gz[4], gn[4];
  #pragma unroll
  for (int i = 0; i < 3; i++) {
    const float* gp = gi + (rowbase + i)*G3;
    gr[i] = gp[d]; gz[i] = gp[256+d]; gn[i] = gp[512+d];
  }
  #pragma unroll 4
  for (int t = 0; t < TT; t++) {
    if (WAIT && t && (t & (CH-1)) == 0) {
      int c = t / CH;
      int nc = c + 2 > NCH ? NCH : c + 2;
      wait_flag(waitf, 2u * (uint32_t)nc);
    }
    const int sl = t & 3;
    const int sl3 = (t + 3) & 3;
    if (t + 3 < TT) {
      const float* gp = gi + (rowbase + t + 3)*G3;
      gr[sl3] = gp[d]; gz[sl3] = gp[256+d]; gn[sl3] = gp[512+d];
    }
    float ar0=0.f, ar1=0.f, az0=0.f, az1=0.f, an0=0.f, an1=0.f;
    const f16x8* hb = (const f16x8*)hbuf[t & 1];
    #pragma unroll
    for (int q = 0; q < 16; q++) {
      f16x8 hv = hb[q];
      f16x8 w0 = wr[q], w1 = wz[q], w2 = wn[q];
      #pragma unroll
      for (int pp = 0; pp < 4; pp++) {
        f16x2 ha; ha[0]=hv[2*pp]; ha[1]=hv[2*pp+1];
        f16x2 vr; vr[0]=w0[2*pp]; vr[1]=w0[2*pp+1];
        f16x2 vz; vz[0]=w1[2*pp]; vz[1]=w1[2*pp+1];
        f16x2 vn; vn[0]=w2[2*pp]; vn[1]=w2[2*pp+1];
        if (pp & 1) { ar1=dot2f(ha,vr,ar1); az1=dot2f(ha,vz,az1); an1=dot2f(ha,vn,an1); }
        else        { ar0=dot2f(ha,vr,ar0); az0=dot2f(ha,vz,az0); an0=dot2f(ha,vn,an0); }
      }
    }
    float rr = sigmoidf_((ar0+ar1) + gr[sl]);
    float zz = sigmoidf_((az0+az1) + gz[sl]);
    float nv = tanhf_(gn[sl] + rr * ((an0+an1) + bn));
    float hn = (1.f - zz) * nv + zz * h_old;
    h_old = hn;
    if (d < 128) hbuf[(t & 1) ^ 1][d] = (f16)hn;
    size_t o = (rowbase + t)*DM + d;
    if (WF) hf_out[o] = hn;
    if (WH) hh_out[o] = (f16)hn;
    if (PUB && ((t + 1) & (CH-1)) == 0) {
      __syncthreads();                    // drains vmcnt: all waves' stores in L2
      if (d == 0)
        __hip_atomic_store(pubf, (uint32_t)(t + 1), __ATOMIC_RELEASE,
                           __HIP_MEMORY_SCOPE_AGENT);
    } else {
      lds_barrier();                      // new h visible; prefetch stays in flight
    }
  }
}

// ---------------- chunked gate-preact GEMM: Y[rows][768] = A[rows][K] @ Bw^T + bias ----------------
// KT = K/32. 2 blocks/batch (nh = n-half of 384 cols); per chunk: 16 rows.
template<int KT>
__device__ __forceinline__ void gi_gemm_chunks(int b, int nh, int t,
    const f16* __restrict__ A, const f16* __restrict__ Bw,
    const float* __restrict__ bias, float* __restrict__ Y,
    const uint32_t* waitf, uint32_t* pubf)
{
  const int K = KT * 32;
  const int lane = t & 63, wave = t >> 6;
  const int n0w = nh*384 + wave*96;
  const int l15 = lane & 15, quad = lane >> 4;
  const int kq = quad*8, rb = quad*4;
  for (int c = 0; c < NCH; c++) {
    if (waitf) wait_flag(waitf, (uint32_t)((c+1)*CH));
    const f16* Ap = A + ((size_t)b*TT + c*CH + l15)*K + kq;
    f32x4 acc[6] = {};
    #pragma unroll
    for (int kt = 0; kt < KT; kt++) {
      f16x8 a = *(const f16x8*)(Ap + kt*32);
      #pragma unroll
      for (int nt = 0; nt < 6; nt++) {
        const f16* Bp = Bw + (size_t)(n0w + nt*16 + l15)*K + kq + kt*32;
        acc[nt] = __builtin_amdgcn_mfma_f32_16x16x32_f16(a, *(const f16x8*)Bp, acc[nt], 0,0,0);
      }
    }
    #pragma unroll
    for (int nt = 0; nt < 6; nt++) {
      int n = n0w + nt*16 + l15;
      float bb = bias[n];
      #pragma unroll
      for (int r = 0; r < 4; r++)
        Y[((size_t)b*TT + c*CH + rb + r)*G3 + n] = acc[nt][r] + bb;
    }
    __syncthreads();                     // drains vmcnt: all waves' stores in L2
    if (t == 0)
      __hip_atomic_fetch_add(pubf, 1u, __ATOMIC_RELEASE, __HIP_MEMORY_SCOPE_AGENT);
  }
}

// ---------------- full pipelined kernel (prep MERGED; round-17) ----------------
// Wait-invariant: every wait targets strictly LOWER block IDs.
// [0,96): whh0 f2h (pub FWHH0)      [96,192): wih1 f2h (pub FWIH1)
// [192,288): whh1 f2h (pub FWHH1)   [288,384): xh96 pack (pub FX)
// [384,672): Wc fold (pub FWC)      [672,675): cbc fold (pub FWC)   675: cb1 (pub FCB1)
// [676,692): gi0 GEMM K=96 (wait FX=96,FWC=291; pub f3)
// [692,700): L0 scan (wait FWHH0=96, f3 chunks; pub f0)
// [700,716): gi1 GEMM (wait FWIH1=96,FCB1=1, f0 chunks; pub f1)
// [716,724): L1 scan (wait FWHH1=96, f1 chunks; pub f2)
// [724,788): packw2   [788,804): w3h   [804,860): split_w1 (pub FW1)   [860,910): temb
// [910,974): LN+hpre (wait FW1=56 + f2 chunks)   [974,+2048): noise table
// Flags zeroed by stream-ordered hipMemsetAsync before this launch.
// ALIAS: gi1 == gi0 buffer (f0-wait-ordered; L0's +3 prefetch lands in chunk c+1).
__global__ __launch_bounds__(256, 1)
void k_scan_pipe(float* __restrict__ gi,                  // gi0 (gi1 aliases)
                 const f16* __restrict__ whh0h, const float* __restrict__ bhh0,
                 f16* __restrict__ h0h,                   // L0 out (hAh)
                 const f16* __restrict__ xh96, const f16* __restrict__ Wc,
                 const float* __restrict__ cbc,
                 const f16* __restrict__ wih1h, const float* __restrict__ cb1,
                 const f16* __restrict__ whh1h, const float* __restrict__ bhh1,
                 float* __restrict__ hA,                  // L1 out (f32)
                 const float* __restrict__ ln_g, const float* __restrict__ ln_b,
                 const f16* __restrict__ w1hh, f16* __restrict__ hpreh,
                 uint32_t* __restrict__ flags,
                 const float* __restrict__ dw2, unsigned char* __restrict__ w2p,
                 const float* __restrict__ dw3, f16* __restrict__ w3h,
                 const float* __restrict__ dw1, f16* __restrict__ w1x,
                 f16* __restrict__ w1h,
                 const float* __restrict__ tw1, const float* __restrict__ tb1,
                 const float* __restrict__ tw2, const float* __restrict__ tb2,
                 const float* __restrict__ db1, float* __restrict__ tv,
                 f16* __restrict__ nzb, DiffParams P,
                 const float* __restrict__ z, const float* __restrict__ o,
                 const float* __restrict__ in_w, const float* __restrict__ in_b,
                 const float* __restrict__ wih0, const float* __restrict__ whh0,
                 const float* __restrict__ bih0, const float* __restrict__ bhh0f,
                 const float* __restrict__ wih1, const float* __restrict__ whh1,
                 const float* __restrict__ bih1, const float* __restrict__ bhh1f,
                 f16* __restrict__ whh0h_w, f16* __restrict__ wih1h_w,
                 f16* __restrict__ whh1h_w, f16* __restrict__ xh96_w,
                 f16* __restrict__ Wc_w, float* __restrict__ cbc_w,
                 float* __restrict__ cb1_w)
{
  __shared__ f16 hbuf[2][128];
  __shared__ float e[DM], te[DM];
  __shared__ f16 hc[16][264];
  const int blk = blockIdx.x, t = threadIdx.x;
  if (blk < 96) {
    for (int i = blk*256 + t; i < G3*DM; i += 96*256) whh0h_w[i] = (f16)whh0[i];
    pub_count(&flags[FWHH0]);
  } else if (blk < 192) {
    for (int i = (blk-96)*256 + t; i < G3*DM; i += 96*256) wih1h_w[i] = (f16)wih1[i];
    pub_count(&flags[FWIH1]);
  } else if (blk < 288) {
    for (int i = (blk-192)*256 + t; i < G3*DM; i += 96*256) whh1h_w[i] = (f16)whh1[i];
    pub_count(&flags[FWHH1]);
  } else if (blk < 384) {
    // pack x = concat(z,o) -> f16 [4096][96]
    for (int i = (blk-288)*256 + t; i < MM*OUTD; i += 96*256) {
      int row = i / OUTD, c = i % OUTD;
      float v = (c < 64) ? z[row*64 + c] : o[row*32 + c - 64];
      xh96_w[i] = (f16)v;
    }
    pub_count(&flags[FX]);
  } else if (blk < 672) {
    // Wc[n][k] = sum_d wih0[n][d] * in_w[d][k]   (768x96 outputs, dot256)
    int idx = (blk-384)*256 + t;          // 0..73727
    int n = idx / OUTD, k = idx % OUTD;
    const float* wr = wih0 + (size_t)n*DM;
    float acc = 0.f;
    #pragma unroll 8
    for (int d = 0; d < DM; d++) acc = fmaf(wr[d], in_w[d*OUTD + k], acc);
    Wc_w[idx] = (f16)acc;
    pub_count(&flags[FWC]);
  } else if (blk < 675) {
    // cbc[j] = wih0[j]@in_b + bih0[j] + (j<512? bhh0[j]:0)
    int j = (blk-672)*256 + t;            // 0..767
    const float* wr = wih0 + (size_t)j*DM;
    float acc = bih0[j] + (j < 512 ? bhh0f[j] : 0.f);
    #pragma unroll 8
    for (int d = 0; d < DM; d++) acc = fmaf(wr[d], in_b[d], acc);
    cbc_w[j] = acc;
    pub_count(&flags[FWC]);
  } else if (blk == 675) {
    for (int j = t; j < G3; j += 256) cb1_w[j] = bih1[j] + (j < 512 ? bhh1f[j] : 0.f);
    pub_count(&flags[FCB1]);
  } else if (blk < 692) {
    const int g = blk - 676, b = g >> 1, nh = g & 1;
    wait_flag(&flags[FX], 96u);
    wait_flag(&flags[FWC], 291u);        // 288 Wc blocks + 3 cbc blocks
    gi_gemm_chunks<3>(b, nh, t, xh96, Wc, cbc, gi, nullptr, &flags[F3 + b]);
  } else if (blk < 700) {
    const int b = blk - 692;
    wait_flag(&flags[FWHH0], 96u);       // whh0h ready (weights preloaded at scan entry)
    scan_body<false, true, true, true>(b, t, gi, whh0h, bhh0,
                                       nullptr, h0h, hbuf,
                                       &flags[F0 + b], &flags[F3 + b]);
  } else if (blk < 716) {
    const int g = blk - 700, b = g >> 1, nh = g & 1;
    wait_flag(&flags[FWIH1], 96u);
    wait_flag(&flags[FCB1], 1u);
    gi_gemm_chunks<8>(b, nh, t, h0h, wih1h, cb1, gi, &flags[F0 + b], &flags[F1 + b]);
  } else if (blk < 724) {
    const int b = blk - 716;
    wait_flag(&flags[FWHH1], 96u);
    scan_body<true, false, true, true>(b, t, gi, whh1h, bhh1,
                                       hA, nullptr, hbuf,
                                       &flags[F2 + b], &flags[F1 + b]);
  } else if (blk < 788) {
    // pack den_w2 fragment-order fp8 (grid-stride, 64 blocks over 512*512)
    for (int i = (blk - 724)*256 + t; i < 512*512; i += 64*256) {
      int j = i & 7;
      int lane = (i >> 3) & 63;
      int tk = i >> 9;
      int tt = tk >> 4, kt = tk & 15;
      int row = tt*16 + (lane & 15);
      int col = kt*32 + (lane >> 4)*8 + j;
      w2p[i] = f32_to_e4m3(dw2[row*512 + col]);
    }
  } else if (blk < 804) {
    for (int i = (blk - 788)*256 + t; i < OUTD*HH2; i += 16*256) w3h[i] = (f16)dw3[i];
  } else if (blk < 860) {
    // den_w1 [512][608] -> W1x [512][96], W1h [512][256]; publish w1done
    for (int i = (blk - 804)*256 + t; i < 512*96 + 512*256; i += 56*256) {
      if (i < 512*96) { int n = i/96, k = i%96; w1x[i] = (f16)dw1[n*608 + k]; }
      else { int jj = i - 512*96; int n = jj/256, k = jj%256; w1h[jj] = (f16)dw1[n*608 + 96 + k]; }
    }
    pub_count(&flags[FW1]);
  } else if (blk < 910) {
    // time embedding for step s: tv[s][512] = W1t @ t_emb(s) + den_b1
    const int s = blk - 860;
    float tn = (float)s / 49.f;
    { float v = tn * tw1[t] + tb1[t]; e[t] = siluf_(v); }
    __syncthreads();
    {
      float acc = tb2[t];
      const float* wr = tw2 + t*DM;
      #pragma unroll 8
      for (int k = 0; k < DM; k++) acc = fmaf(e[k], wr[k], acc);
      te[t] = acc;
    }
    __syncthreads();
    for (int n = t; n < HH2; n += 256) {
      float a2 = db1[n];
      const float* r = dw1 + n*608 + 352;
      #pragma unroll 8
      for (int k = 0; k < DM; k++) a2 = fmaf(te[k], r[k], a2);
      tv[s*HH2 + n] = a2;
    }
  } else if (blk < 974) {
    // LN + hpre GEMM: 64 blocks x 4 chunks (batch b, chunks 4*cg..4*cg+3)
    const int g = blk - 910, b = g >> 3, cg = g & 7;
    wait_flag(&flags[FW1], 56u);                       // w1h complete (56 split blocks)
    const int wave = t >> 6, lane = t & 63;
    float gl0=ln_g[lane], gl1=ln_g[lane+64], gl2=ln_g[lane+128], gl3=ln_g[lane+192];
    float bl0=ln_b[lane], bl1=ln_b[lane+64], bl2=ln_b[lane+128], bl3=ln_b[lane+192];
    for (int k4 = 0; k4 < 4; k4++) {
      const int c = cg*4 + k4;
      wait_flag(&flags[F2 + b], (uint32_t)((c+1)*CH));   // L1 hA rows ready
      const size_t R0 = (size_t)b*TT + c*CH;
      #pragma unroll
      for (int rr = 0; rr < 4; rr++) {
        int r = wave*4 + rr;
        const float* row = hA + (R0 + r)*DM;
        float v0=row[lane], v1=row[lane+64], v2=row[lane+128], v3=row[lane+192];
        float s = v0+v1+v2+v3;
        #pragma unroll
        for (int o2 = 32; o2; o2 >>= 1) s += __shfl_xor(s, o2, 64);
        float mu = s * (1.f/256.f);
        float d0=v0-mu, d1=v1-mu, d2=v2-mu, d3=v3-mu;
        float q = d0*d0+d1*d1+d2*d2+d3*d3;
        #pragma unroll
        for (int o2 = 32; o2; o2 >>= 1) q += __shfl_xor(q, o2, 64);
        float rs = rsqrtf(q*(1.f/256.f) + 1e-5f);
        hc[r][lane]     = (f16)(d0*rs*gl0 + bl0);
        hc[r][lane+64]  = (f16)(d1*rs*gl1 + bl1);
        hc[r][lane+128] = (f16)(d2*rs*gl2 + bl2);
        hc[r][lane+192] = (f16)(d3*rs*gl3 + bl3);
      }
      __syncthreads();
      const int l15 = lane & 15, quad = lane >> 4;
      const int kq = quad*8, rb = quad*4;
      f32x4 acc[8] = {};
      #pragma unroll
      for (int kt = 0; kt < 8; kt++) {
        f16x8 a = *(const f16x8*)&hc[l15][kt*32 + kq];
        #pragma unroll
        for (int nt = 0; nt < 8; nt++) {
          const f16* Bp = w1hh + (size_t)(wave*128 + nt*16 + l15)*DM + kq + kt*32;
          acc[nt] = __builtin_amdgcn_mfma_f32_16x16x32_f16(a, *(const f16x8*)Bp, acc[nt], 0,0,0);
        }
      }
      #pragma unroll
      for (int nt = 0; nt < 8; nt++) {
        int n = wave*128 + nt*16 + l15;
        #pragma unroll
        for (int r = 0; r < 4; r++)
          hpreh[(R0 + rb + r)*HH2 + n] = (f16)acc[nt][r];
      }
      __syncthreads();            // hc reused next chunk
    }
  } else {
    // noise table: 2048 blocks x 9792 contiguous elems (2048*9792 == NZTOT)
    long base = (long)(blk - 974) * 9792;
    long end  = base + 9792;
    while (base < end) {
      int s = (int)(base / NTOT);
      long segend = (long)(s + 1) * NTOT;
      if (segend > end) segend = end;
      uint32_t kk0 = (s < NSTEPS) ? P.k0[s] : P.xk0;
      uint32_t kk1 = (s < NSTEPS) ? P.k1[s] : P.xk1;
      long sbase = (long)s * NTOT;
      for (long ee = base + t; ee < segend; ee += 256)
        nzb[ee] = (f16)jax_normal_elem(kk0, kk1, (uint32_t)(ee - sbase));
      base = segend;
    }
  }
}

// ---------------- fused 50-step diffusion loop (round-10 best, unchanged) ----------------
#define YSTR  520   // f16 stride: 260 dw == 4 (mod 32) -> conflict-minimal b128
#define XHSTR 104   // f16 stride: 52 dw == 20 (mod 32)
#define W3STR 520

__device__ __forceinline__ int y1p_swz(int g) {
  return ((g >> 2) & 7) | ((g & 3) << 3) | (g & 32);
}

__global__ __launch_bounds__(1024)
void k_diff(const f16* __restrict__ w1x,   // [512][96]
            const unsigned char* __restrict__ w2p, // fragment-packed fp8 [512*512]
            const f16* __restrict__ w3h,   // [96][512]
            const f16* __restrict__ hpreh, // [4096][512]
            const float* __restrict__ tv,  // [50][512]
            const float* __restrict__ db2, // [512]
            const float* __restrict__ db3, // [96]
            const f16* __restrict__ nzb,   // [51][4096][96] precomputed noise
            float* __restrict__ out,
            DiffParams P)
{
  __shared__ unsigned char y1p_l[16*512]; // 8 KB: y1 fp8 A-frags, granule-swizzled
  __shared__ f16 y2_l[16*YSTR];     // 16.6 KB
  __shared__ f16 xh_l[16*XHSTR];    // 3.3 KB, x in A-layout
  __shared__ f16 w3_l[96*W3STR];    // 97.5 KB, step-invariant

  const int t = threadIdx.x;
  const int lane = t & 63;
  const int wave = t >> 6;          // 0..15
  const int quad = lane >> 4;
  const int l15 = lane & 15;
  const int m0 = blockIdx.x * 16;
  const int n0w = wave * 32;        // Y1/Y2: 16 waves x 32 cols (2 tiles)

  const int t0 = 2*wave, t1 = 2*wave + 1;   // this wave's two n-tiles
  const int lsw8 = y1p_swz(lane) << 3;      // consumer granule offset (bytes)

  // ---- preload step-invariant w2 B-fragments (spill to L2 scratch; reload coalesced)
  long w2f0[16], w2f1[16];
  {
    const unsigned char* p0 = w2p + (((size_t)(t0*16)*64 + lane) << 3);
    const unsigned char* p1 = w2p + (((size_t)(t1*16)*64 + lane) << 3);
    #pragma unroll
    for (int kt = 0; kt < 16; kt++) {
      w2f0[kt] = *(const long*)(p0 + kt*512);
      w2f1[kt] = *(const long*)(p1 + kt*512);
    }
  }
  // ---- preload this lane's hp epilogue values (8 regs, direct from global)
  float hpr[2][4];
  #pragma unroll
  for (int nt = 0; nt < 2; nt++)
    #pragma unroll
    for (int r = 0; r < 4; r++)
      hpr[nt][r] = (float)hpreh[(long)(m0 + quad*4 + r)*HH2 + n0w + nt*16 + l15];
  // ---- hoist db2 biases (step-invariant)
  const float db2r0 = db2[n0w + l15];
  const float db2r1 = db2[n0w + 16 + l15];

  // ---- stage w3 into LDS once (96 rows x 64 vec8)
  #pragma unroll
  for (int i = 0; i < 6; i++) {
    int v = t + i*1024;             // 0..6143
    int row = v >> 6, c8 = v & 63;
    *((f16x8*)&w3_l[row*W3STR] + c8) = *((const f16x8*)(w3h + row*HH2) + c8);
  }

  // ---- x0 init from precomputed slot 50: waves 0..5 own x in registers
  const int neps = wave * 16 + l15;
  float xreg[4];
  if (wave < 6) {
    #pragma unroll
    for (int r = 0; r < 4; r++) {
      int ml = quad*4 + r;
      float v = (float)nzb[(size_t)NSTEPS*NTOT + (size_t)(m0 + ml)*OUTD + neps];
      xreg[r] = v;
      xh_l[ml*XHSTR + neps] = (f16)v;
    }
  }

  for (int s = NSTEPS-1; s >= 0; --s) {
    __syncthreads();                // xh ready (stages/x0 on first iter); y1p_l free
    // ---- issue this step's noise loads NOW (consumed 2 phases later in EPS)
    f16 nzr[4];
    if (wave < 6 && s > 0) {
      #pragma unroll
      for (int r = 0; r < 4; r++)
        nzr[r] = nzb[(size_t)s*NTOT + (size_t)(m0 + quad*4 + r)*OUTD + neps];
    }
    // ---- Y1: K=96, 6 MFMA/wave (f16)
    {
      f32x4 acc[2] = {};
      #pragma unroll
      for (int kt = 0; kt < 3; kt++) {
        f16x8 a = *(const f16x8*)&xh_l[l15*XHSTR + kt*32 + quad*8];
        f16x8 b0 = *(const f16x8*)&w1x[(n0w + l15)*96 + kt*32 + quad*8];
        f16x8 b1 = *(const f16x8*)&w1x[(n0w + 16 + l15)*96 + kt*32 + quad*8];
        acc[0] = __builtin_amdgcn_mfma_f32_16x16x32_f16(a, b0, acc[0], 0,0,0);
        acc[1] = __builtin_amdgcn_mfma_f32_16x16x32_f16(a, b1, acc[1], 0,0,0);
      }
      // y1[ml][n] -> packed frag at swizzled granule: logical G = ml|lp, physical swz(G)
      #pragma unroll
      for (int nt = 0; nt < 2; nt++) {
        int n = n0w + nt*16 + l15;
        float tvv = tv[s*HH2 + n];
        int lp = ((nt*2 + (l15>>3)) << 4);
        int jp = l15 & 7;
        #pragma unroll
        for (int r = 0; r < 4; r++) {
          float v = (nt ? acc[1][r] : acc[0][r]) + hpr[nt][r] + tvv;
          int ml = quad*4 + r;
          y1p_l[wave*512 + (y1p_swz(ml | lp) << 3) + jp] = f32_to_e4m3(siluf_(v));
        }
      }
    }
    lds_barrier();                  // y1 complete (LDS-only dependency)
    // ---- Y2: K=512, 32 fp8-MFMA/wave
    {
      f32x4 acc2[2] = {};
      #pragma unroll
      for (int kt = 0; kt < 16; kt++) {
        long a  = *(const long*)(y1p_l + kt*512 + lsw8);
        acc2[0] = __builtin_amdgcn_mfma_f32_16x16x32_fp8_fp8(a, w2f0[kt], acc2[0], 0,0,0);
        acc2[1] = __builtin_amdgcn_mfma_f32_16x16x32_fp8_fp8(a, w2f1[kt], acc2[1], 0,0,0);
      }
      #pragma unroll
      for (int nt = 0; nt < 2; nt++) {
        int n = n0w + nt*16 + l15;
        float bb = nt ? db2r1 : db2r0;
        #pragma unroll
        for (int r = 0; r < 4; r++) {
          int ml = quad*4 + r;
          y2_l[ml*YSTR + n] = (f16)siluf_((nt ? acc2[1][r] : acc2[0][r]) + bb);
        }
      }
    }
    lds_barrier();                  // y2 complete (LDS-only dependency)
    // ---- EPS + x-update (waves 0-5); waves 6-15 idle to the top barrier
    if (wave < 6) {
      f32x4 acc3 = {};
      #pragma unroll 8
      for (int kt = 0; kt < 16; kt++) {
        f16x8 a = *(const f16x8*)&y2_l[l15*YSTR + kt*32 + quad*8];
        f16x8 b = *(const f16x8*)&w3_l[(wave*16 + l15)*W3STR + kt*32 + quad*8];
        acc3 = __builtin_amdgcn_mfma_f32_16x16x32_f16(a, b, acc3, 0,0,0);
      }
      float sra = P.sra[s], coeff = P.coeff[s], sb = P.sb[s];
      float b3 = db3[neps];
      #pragma unroll
      for (int r = 0; r < 4; r++) {
        int ml = quad*4 + r;
        float eps = acc3[r] + b3;
        float mean = sra * (xreg[r] - coeff * eps);
        float xn = mean;
        if (s > 0) xn = mean + sb * (float)nzr[r];
        xreg[r] = xn;
        xh_l[ml*XHSTR + neps] = (f16)xn;
      }
    }
  }
  // ---- output from registers: [...,:64] then [...,64:96]
  if (wave < 6) {
    #pragma unroll
    for (int r = 0; r < 4; r++) {
      long m = m0 + quad*4 + r;
      if (neps < 64) out[m*64 + neps] = xreg[r];
      else out[(long)MM*64 + m*32 + (neps - 64)] = xreg[r];
    }
  }
}

// ---------------- host ----------------
extern "C" void kernel_launch(void* const* d_in, const int* in_sizes, int n_in,
                              void* d_out, int out_size, void* d_ws, size_t ws_size,
                              hipStream_t stream)
{
  (void)in_sizes; (void)n_in; (void)out_size; (void)ws_size;
  const float* z_seq = (const float*)d_in[0];
  const float* o_seq = (const float*)d_in[1];
  const float* in_w  = (const float*)d_in[2];
  const float* in_b  = (const float*)d_in[3];
  const float* wih0  = (const float*)d_in[4];
  const float* whh0  = (const float*)d_in[5];
  const float* bih0  = (const float*)d_in[6];
  const float* bhh0  = (const float*)d_in[7];
  const float* wih1  = (const float*)d_in[8];
  const float* whh1  = (const float*)d_in[9];
  const float* bih1  = (const float*)d_in[10];
  const float* bhh1  = (const float*)d_in[11];
  const float* ln_g  = (const float*)d_in[12];
  const float* ln_b  = (const float*)d_in[13];
  const float* tw1   = (const float*)d_in[14];
  const float* tb1   = (const float*)d_in[15];
  const float* tw2   = (const float*)d_in[16];
  const float* tb2   = (const float*)d_in[17];
  const float* dw1   = (const float*)d_in[18];
  const float* db1   = (const float*)d_in[19];
  const float* dw2   = (const float*)d_in[20];
  const float* db2   = (const float*)d_in[21];
  const float* dw3   = (const float*)d_in[22];
  const float* db3   = (const float*)d_in[23];

  // workspace carve-up
  char* base = (char*)d_ws;
  size_t off = 0;
  auto alloc = [&](size_t bytes) -> void* {
    void* p = base + off;
    off = (off + bytes + 255) & ~(size_t)255;
    return p;
  };
  float* gi     = (float*)alloc((size_t)MM*G3*4);   // gi0; gi1 aliases (flag-ordered)
  float* hA     = (float*)alloc((size_t)MM*DM*4);
  f16*   hAh    = (f16*)  alloc((size_t)MM*DM*2);   // L0 h0 output
  f16*   hpreh  = (f16*)  alloc((size_t)MM*HH2*2);
  float* tv     = (float*)alloc((size_t)NSTEPS*HH2*4);
  f16*   whh0h  = (f16*)  alloc((size_t)G3*DM*2);
  f16*   wih1h  = (f16*)  alloc((size_t)G3*DM*2);
  f16*   whh1h  = (f16*)  alloc((size_t)G3*DM*2);
  f16*   w1xh   = (f16*)  alloc((size_t)HH2*96*2);
  f16*   w1hh   = (f16*)  alloc((size_t)HH2*DM*2);
  unsigned char* w2p = (unsigned char*)alloc((size_t)HH2*HH2);
  f16*   w3h    = (f16*)  alloc((size_t)OUTD*HH2*2);
  f16*   xh96   = (f16*)  alloc((size_t)MM*OUTD*2);
  f16*   Wc     = (f16*)  alloc((size_t)G3*OUTD*2);
  float* cbc    = (float*)alloc((size_t)G3*4);
  float* cb1    = (float*)alloc((size_t)G3*4);
  uint32_t* flags = (uint32_t*)alloc(256);
  f16*   nzb    = (f16*)  alloc((size_t)NZTOT*2);   // 40.1 MB noise table

  // host-side diffusion schedule + keys
  DiffParams P;
  {
    float ab = 1.f;
    float delta = (0.02f - 1e-4f) / 49.f;
    for (int i = 0; i < NSTEPS; i++) {
      float bt = 1e-4f + delta * (float)i;
      float al = 1.f - bt;
      ab *= al;
      P.sra[i]   = sqrtf(1.f / al);
      P.coeff[i] = bt / sqrtf(1.f - ab);
      P.sb[i]    = sqrtf(bt);
    }
    for (int s = 0; s < NSTEPS; s++) {
      uint32_t o0, o1;
      tf2x32(0u, 42u, 0u, (uint32_t)s, o0, o1);
      P.k0[s] = o0; P.k1[s] = o1;
    }
    uint32_t o0, o1;
    tf2x32(0u, 42u, 0u, (uint32_t)NSTEPS, o0, o1);
    P.xk0 = o0; P.xk1 = o1;
  }

  // 1. zero the flags (stream-ordered, graph-capture-safe)
  hipMemsetAsync(flags, 0, 256, stream);
  // 2. SINGLE MEGA-PIPELINE: prep bands (f2h, fold, pack) -> gi0 || L0 || gi1 || L1
  //    || LN+hpre, + k_diff prep + noise table; all flag-gated, lower-ID waits only
  k_scan_pipe<<<974 + 2048, 256, 0, stream>>>(
      gi, whh0h, bhh0, hAh, xh96, Wc, cbc,
      wih1h, cb1, whh1h, bhh1, hA,
      ln_g, ln_b, w1hh, hpreh, flags,
      dw2, w2p, dw3, w3h, dw1, w1xh, w1hh,
      tw1, tb1, tw2, tb2, db1, tv, nzb, P,
      z_seq, o_seq, in_w, in_b,
      wih0, whh0, bih0, bhh0,
      wih1, whh1, bih1, bhh1,
      whh0h, wih1h, whh1h, xh96, Wc, cbc, cb1);
  // 3. fused 50-step diffusion sampling (RNG-free)
  k_diff<<<256, 1024, 0, stream>>>(w1xh, w2p, w3h, hpreh, tv, db2, db3, nzb,
                                   (float*)d_out, P);
}

// Round 18
// 809.627 us; speedup vs baseline: 1.0341x; 1.0341x over previous
//
#include <hip/hip_runtime.h>
#include <stdint.h>
#include <math.h>

// ---------------- problem constants ----------------
#define DM    256      // D_MODEL
#define G3    768      // 3*D
#define TT    512      // T
#define BB    8        // B
#define MM    4096     // B*T
#define OUTD  96       // LATENT+OBJ
#define HH2   512      // 2*D
#define NSTEPS 50
#define NTOT  (MM*OUTD)   // 393216
#define NZTOT ((NSTEPS+1)*NTOT)  // 51 slots: s=0..49 step noise, slot 50 = x0
#define CH    16       // pipeline chunk (timesteps)
#define NCH   (TT/CH)  // 32 chunks
// flag layout: [0..8) f0 = L0 h0 progress (steps); [8..16) f1 = gi1 chunks (2/chunk);
// [16..24) f2 = L1 hA progress (steps); [24..32) f3 = gi0 chunks (2/chunk); [32] w1done
#define F0 0
#define F1 8
#define F2 16
#define F3 24
#define FW1 32

typedef _Float16 f16;
typedef _Float16 f16x2 __attribute__((ext_vector_type(2)));
typedef _Float16 f16x8 __attribute__((ext_vector_type(8)));
typedef float    f32x4 __attribute__((ext_vector_type(4)));

// ---------------- LDS-only barrier ----------------
__device__ __forceinline__ void lds_barrier() {
  asm volatile("s_waitcnt lgkmcnt(0)" ::: "memory");
  __builtin_amdgcn_s_barrier();
}

// ---------------- block-cooperative flag wait (single poller; round-14 proven) ----------------
__device__ __forceinline__ void wait_flag(const uint32_t* f, uint32_t target) {
  if (threadIdx.x == 0) {
    while (__hip_atomic_load(f, __ATOMIC_RELAXED, __HIP_MEMORY_SCOPE_AGENT) < target)
      __builtin_amdgcn_s_sleep(8);
  }
  __builtin_amdgcn_s_barrier();
  __builtin_amdgcn_fence(__ATOMIC_ACQUIRE, "agent");
}

// ---------------- threefry2x32 (JAX-exact) ----------------
__host__ __device__ inline void tf2x32(uint32_t k0, uint32_t k1,
                                       uint32_t x0, uint32_t x1,
                                       uint32_t& o0, uint32_t& o1)
{
  uint32_t ks2 = k0 ^ k1 ^ 0x1BD11BDAu;
#define ROTL(v,r) (((v)<<(r))|((v)>>(32-(r))))
#define RND(r) { x0 += x1; x1 = ROTL(x1,r); x1 ^= x0; }
  x0 += k0; x1 += k1;
  RND(13) RND(15) RND(26) RND(6)
  x0 += k1;  x1 += ks2 + 1u;
  RND(17) RND(29) RND(16) RND(24)
  x0 += ks2; x1 += k0 + 2u;
  RND(13) RND(15) RND(26) RND(6)
  x0 += k0;  x1 += k1 + 3u;
  RND(17) RND(29) RND(16) RND(24)
  x0 += k1;  x1 += ks2 + 4u;
  RND(13) RND(15) RND(26) RND(6)
  x0 += ks2; x1 += k0 + 5u;
  o0 = x0; o1 = x1;
#undef RND
#undef ROTL
}

// bits -> N(0,1), exactly JAX: uniform in [-0.99999994, 1) then sqrt(2)*erfinv (XLA ErfInv32)
__device__ inline float bits_to_normal(uint32_t bits) {
  float f = __uint_as_float((bits >> 9) | 0x3F800000u) - 1.0f;  // [0,1)
  const float lo = -0.99999994f;
  float u = fmaxf(lo, f * 2.0f + lo);
  float w = -log1pf(-u * u);
  float p;
  if (w < 5.0f) {
    w -= 2.5f;
    p = 2.81022636e-08f;
    p = fmaf(p, w, 3.43273939e-07f);
    p = fmaf(p, w, -3.5233877e-06f);
    p = fmaf(p, w, -4.39150654e-06f);
    p = fmaf(p, w, 0.00021858087f);
    p = fmaf(p, w, -0.00125372503f);
    p = fmaf(p, w, -0.00417768164f);
    p = fmaf(p, w, 0.246640727f);
    p = fmaf(p, w, 1.50140941f);
  } else {
    w = sqrtf(w) - 3.0f;
    p = -0.000200214257f;
    p = fmaf(p, w, 0.000100950558f);
    p = fmaf(p, w, 0.00134934322f);
    p = fmaf(p, w, -0.00367342844f);
    p = fmaf(p, w, 0.00573950773f);
    p = fmaf(p, w, -0.0076224613f);
    p = fmaf(p, w, 0.00943887047f);
    p = fmaf(p, w, 1.00167406f);
    p = fmaf(p, w, 2.83297682f);
  }
  float ei = p * u;
  return 1.41421356f * ei;
}

// partitionable threefry, 32-bit draw: counter=(hi=0, lo=e), bits = o0 ^ o1
__device__ inline float jax_normal_elem(uint32_t k0, uint32_t k1, uint32_t e) {
  uint32_t o0, o1;
  tf2x32(k0, k1, 0u, e, o0, o1);
  return bits_to_normal(o0 ^ o1);
}

// ---------------- small helpers ----------------
__device__ inline float dot2f(f16x2 a, f16x2 b, float c) {
#if __has_builtin(__builtin_amdgcn_fdot2)
  return __builtin_amdgcn_fdot2(a, b, c, false);
#else
  return c + (float)a[0]*(float)b[0] + (float)a[1]*(float)b[1];
#endif
}
__device__ inline float sigmoidf_(float x) { return 1.f / (1.f + __expf(-x)); }
__device__ inline float siluf_(float x)    { return x / (1.f + __expf(-x)); }
// fast tanh via single v_exp: tanh(x) = sign(x) * (1-e)/(1+e), e = exp(-2|x|)
__device__ inline float tanhf_(float x) {
  float e = __expf(-2.f * fabsf(x));
  float t = (1.f - e) / (1.f + e);
  return copysignf(t, x);
}

// fp32 -> OCP e4m3 (RNE). HW cvt when available, else software RNE.
__device__ inline unsigned char f32_to_e4m3(float f) {
#if __has_builtin(__builtin_amdgcn_cvt_pk_fp8_f32)
  int p = __builtin_amdgcn_cvt_pk_fp8_f32(f, f, 0, false);
  return (unsigned char)(p & 0xff);
#else
  uint32_t u = __float_as_uint(f);
  unsigned char s = (unsigned char)((u >> 24) & 0x80);
  float af = fabsf(f);
  if (!(af == af)) return (unsigned char)(s | 0x7f);
  if (af >= 448.f) return (unsigned char)(s | 0x7e);      // sat to max finite
  if (af < 0.0078125f) {                                  // < 2^-7: subnormal range
    int q = (int)rintf(af * 512.f);                       // step 2^-9
    return (unsigned char)(s | q);
  }
  int e; float m = frexpf(af, &e);                        // af = m*2^e, m in [0.5,1)
  int mant = (int)rintf(m * 16.f);                        // 8..16 (RNE)
  if (mant == 16) { mant = 8; e += 1; }
  int E = e - 1 + 7;                                      // biased exponent
  if (E <= 0) { int q = (int)rintf(af * 512.f); return (unsigned char)(s | q); }
  return (unsigned char)(s | (E << 3) | (mant - 8));
#endif
}

// ---------------- diffusion schedule / keys ----------------
struct DiffParams {
  float sra[NSTEPS], coeff[NSTEPS], sb[NSTEPS];
  uint32_t k0[NSTEPS], k1[NSTEPS];
  uint32_t xk0, xk1;
};

// ---------------- GRU scan body v2b + pipeline publish/wait ----------------
template<bool WF, bool WH, bool PUB, bool WAIT>
__device__ __forceinline__ void scan_body(int b, int d,
    const float* __restrict__ gi, const f16* __restrict__ whh,
    const float* __restrict__ bhh,
    float* __restrict__ hf_out, f16* __restrict__ hh_out,
    f16 (*hbuf)[128], uint32_t* pubf, const uint32_t* waitf)
{
  f16x8 wr[16], wz[16], wn[16];
  {
    const f16x8* pr = (const f16x8*)(whh + (size_t)d*DM);
    const f16x8* pz = (const f16x8*)(whh + (size_t)(256+d)*DM);
    const f16x8* pn = (const f16x8*)(whh + (size_t)(512+d)*DM);
    #pragma unroll
    for (int q = 0; q < 16; q++) { wr[q]=pr[q]; wz[q]=pz[q]; wn[q]=pn[q]; }
  }
  if (d < 128) { hbuf[0][d] = (f16)0.f; hbuf[1][d] = (f16)0.f; }
  const float bn = bhh[512 + d];
  float h_old = 0.f;
  __syncthreads();
  const size_t rowbase = (size_t)b * TT;
  if (WAIT) wait_flag(waitf, 2u * 2u);   // chunks 0,1 ready (covers prefetch rows 0..2)
  // 4-slot circular gi prefetch (slots static under x4 unroll)
  float gr[4], gz[4], gn[4];
  #pragma unroll
  for (int i = 0; i < 3; i++) {
    const float* gp = gi + (rowbase + i)*G3;
    gr[i] = gp[d]; gz[i] = gp[256+d]; gn[i] = gp[512+d];
  }
  #pragma unroll 4
  for (int t = 0; t < TT; t++) {
    if (WAIT && t && (t & (CH-1)) == 0) {
      int c = t / CH;
      int nc = c + 2 > NCH ? NCH : c + 2;
      wait_flag(waitf, 2u * (uint32_t)nc);
    }
    const int sl = t & 3;
    const int sl3 = (t + 3) & 3;
    if (t + 3 < TT) {
      const float* gp = gi + (rowbase + t + 3)*G3;
      gr[sl3] = gp[d]; gz[sl3] = gp[256+d]; gn[sl3] = gp[512+d];
    }
    float ar0=0.f, ar1=0.f, az0=0.f, az1=0.f, an0=0.f, an1=0.f;
    const f16x8* hb = (const f16x8*)hbuf[t & 1];
    #pragma unroll
    for (int q = 0; q < 16; q++) {
      f16x8 hv = hb[q];
      f16x8 w0 = wr[q], w1 = wz[q], w2 = wn[q];
      #pragma unroll
      for (int pp = 0; pp < 4; pp++) {
        f16x2 ha; ha[0]=hv[2*pp]; ha[1]=hv[2*pp+1];
        f16x2 vr; vr[0]=w0[2*pp]; vr[1]=w0[2*pp+1];
        f16x2 vz; vz[0]=w1[2*pp]; vz[1]=w1[2*pp+1];
        f16x2 vn; vn[0]=w2[2*pp]; vn[1]=w2[2*pp+1];
        if (pp & 1) { ar1=dot2f(ha,vr,ar1); az1=dot2f(ha,vz,az1); an1=dot2f(ha,vn,an1); }
        else        { ar0=dot2f(ha,vr,ar0); az0=dot2f(ha,vz,az0); an0=dot2f(ha,vn,an0); }
      }
    }
    float rr = sigmoidf_((ar0+ar1) + gr[sl]);
    float zz = sigmoidf_((az0+az1) + gz[sl]);
    float nv = tanhf_(gn[sl] + rr * ((an0+an1) + bn));
    float hn = (1.f - zz) * nv + zz * h_old;
    h_old = hn;
    if (d < 128) hbuf[(t & 1) ^ 1][d] = (f16)hn;
    size_t o = (rowbase + t)*DM + d;
    if (WF) hf_out[o] = hn;
    if (WH) hh_out[o] = (f16)hn;
    if (PUB && ((t + 1) & (CH-1)) == 0) {
      __syncthreads();                    // drains vmcnt: all waves' stores in L2
      if (d == 0)
        __hip_atomic_store(pubf, (uint32_t)(t + 1), __ATOMIC_RELEASE,
                           __HIP_MEMORY_SCOPE_AGENT);
    } else {
      lds_barrier();                      // new h visible; prefetch stays in flight
    }
  }
}

// ---------------- chunked gate-preact GEMM: Y[rows][768] = A[rows][K] @ Bw^T + bias ----------------
// KT = K/32. 2 blocks/batch (nh = n-half of 384 cols); per chunk: 16 rows.
template<int KT>
__device__ __forceinline__ void gi_gemm_chunks(int b, int nh, int t,
    const f16* __restrict__ A, const f16* __restrict__ Bw,
    const float* __restrict__ bias, float* __restrict__ Y,
    const uint32_t* waitf, uint32_t* pubf)
{
  const int K = KT * 32;
  const int lane = t & 63, wave = t >> 6;
  const int n0w = nh*384 + wave*96;
  const int l15 = lane & 15, quad = lane >> 4;
  const int kq = quad*8, rb = quad*4;
  for (int c = 0; c < NCH; c++) {
    if (waitf) wait_flag(waitf, (uint32_t)((c+1)*CH));
    const f16* Ap = A + ((size_t)b*TT + c*CH + l15)*K + kq;
    f32x4 acc[6] = {};
    #pragma unroll
    for (int kt = 0; kt < KT; kt++) {
      f16x8 a = *(const f16x8*)(Ap + kt*32);
      #pragma unroll
      for (int nt = 0; nt < 6; nt++) {
        const f16* Bp = Bw + (size_t)(n0w + nt*16 + l15)*K + kq + kt*32;
        acc[nt] = __builtin_amdgcn_mfma_f32_16x16x32_f16(a, *(const f16x8*)Bp, acc[nt], 0,0,0);
      }
    }
    #pragma unroll
    for (int nt = 0; nt < 6; nt++) {
      int n = n0w + nt*16 + l15;
      float bb = bias[n];
      #pragma unroll
      for (int r = 0; r < 4; r++)
        Y[((size_t)b*TT + c*CH + rb + r)*G3 + n] = acc[nt][r] + bb;
    }
    __syncthreads();                     // drains vmcnt: all waves' stores in L2
    if (t == 0)
      __hip_atomic_fetch_add(pubf, 1u, __ATOMIC_RELEASE, __HIP_MEMORY_SCOPE_AGENT);
  }
}

// ---------------- prep kernel: weight f2h + FOLDED inproj weights + x pack + flags ----------------
// gi0 = x@Wc^T + cbc where Wc = wih0 @ in_proj_w (f16 [768][96]) and
// cbc = wih0@in_b + bih0 + bhh0[rz]. x = concat(z,o) packed to f16 [4096][96].
// [0,96): whh0 f2h  [96,192): wih1 f2h  [192,288): whh1 f2h  [288,384): xh96 pack
// [384,672): Wc (1 output/thread, dot256)  [672,675): cbc  675: cb1 + flag zero
__global__ __launch_bounds__(256)
void k_prep(const float* __restrict__ z, const float* __restrict__ o,
            const float* __restrict__ in_w, const float* __restrict__ in_b,
            const float* __restrict__ wih0, const float* __restrict__ whh0,
            f16* __restrict__ whh0h,
            const float* __restrict__ bih0, const float* __restrict__ bhh0,
            const float* __restrict__ wih1, f16* __restrict__ wih1h,
            const float* __restrict__ whh1, f16* __restrict__ whh1h,
            const float* __restrict__ bih1, const float* __restrict__ bhh1,
            float* __restrict__ cb1,
            f16* __restrict__ xh96, f16* __restrict__ Wc, float* __restrict__ cbc,
            uint32_t* __restrict__ flags)
{
  const int blk = blockIdx.x, t = threadIdx.x;
  if (blk < 96) {
    for (int i = blk*256 + t; i < G3*DM; i += 96*256) whh0h[i] = (f16)whh0[i];
  } else if (blk < 192) {
    for (int i = (blk-96)*256 + t; i < G3*DM; i += 96*256) wih1h[i] = (f16)wih1[i];
  } else if (blk < 288) {
    for (int i = (blk-192)*256 + t; i < G3*DM; i += 96*256) whh1h[i] = (f16)whh1[i];
  } else if (blk < 384) {
    // pack x = concat(z,o) -> f16 [4096][96]
    for (int i = (blk-288)*256 + t; i < MM*OUTD; i += 96*256) {
      int row = i / OUTD, c = i % OUTD;
      float v = (c < 64) ? z[row*64 + c] : o[row*32 + c - 64];
      xh96[i] = (f16)v;
    }
  } else if (blk < 672) {
    // Wc[n][k] = sum_d wih0[n][d] * in_w[d][k]   (768x96 outputs, dot256)
    int idx = (blk-384)*256 + t;          // 0..73727
    int n = idx / OUTD, k = idx % OUTD;
    const float* wr = wih0 + (size_t)n*DM;
    float acc = 0.f;
    #pragma unroll 8
    for (int d = 0; d < DM; d++) acc = fmaf(wr[d], in_w[d*OUTD + k], acc);
    Wc[idx] = (f16)acc;
  } else if (blk < 675) {
    // cbc[j] = wih0[j]@in_b + bih0[j] + (j<512? bhh0[j]:0)
    int j = (blk-672)*256 + t;            // 0..767
    const float* wr = wih0 + (size_t)j*DM;
    float acc = bih0[j] + (j < 512 ? bhh0[j] : 0.f);
    #pragma unroll 8
    for (int d = 0; d < DM; d++) acc = fmaf(wr[d], in_b[d], acc);
    cbc[j] = acc;
  } else {
    for (int j = t; j < G3; j += 256) cb1[j] = bih1[j] + (j < 512 ? bhh1[j] : 0.f);
    if (t < 33) flags[t] = 0u;           // re-zeroed EVERY launch (graph-replay safe)
  }
}

// ---------------- full pipelined kernel ----------------
// Wait-invariant: every wait targets strictly LOWER block IDs (round-13 lesson).
// [0,16):  gi0 GEMM K=96 from xh96/Wc (no wait, pub f3)   [16,24): L0 scan (wait f3, pub f0)
// [24,40): gi1 GEMM K=256 (wait f0, pub f1)               [40,48): L1 scan (wait f1, pub f2)
// [48,112): packw2   [112,128): w3h   [128,184): split_w1 (pub FW1)   [184,234): temb
// [234,298): LN+hpre, 64 blocks x 4 chunks (wait FW1 + f2 -- both lower)
// [298,+2048): noise table
// ALIAS: gi1 == gi0 buffer: gi1-GEMM writes chunk c only after L0 consumed those
// rows (f0 wait); L0's +3 prefetch lands in chunk c+1.
__global__ __launch_bounds__(256, 1)
void k_scan_pipe(float* __restrict__ gi,                  // gi0 (gi1 aliases)
                 const f16* __restrict__ whh0h, const float* __restrict__ bhh0,
                 f16* __restrict__ h0h,                   // L0 out (hAh)
                 const f16* __restrict__ xh96, const f16* __restrict__ Wc,
                 const float* __restrict__ cbc,
                 const f16* __restrict__ wih1h, const float* __restrict__ cb1,
                 const f16* __restrict__ whh1h, const float* __restrict__ bhh1,
                 float* __restrict__ hA,                  // L1 out (f32)
                 const float* __restrict__ ln_g, const float* __restrict__ ln_b,
                 const f16* __restrict__ w1hh, f16* __restrict__ hpreh,
                 uint32_t* __restrict__ flags,
                 const float* __restrict__ dw2, unsigned char* __restrict__ w2p,
                 const float* __restrict__ dw3, f16* __restrict__ w3h,
                 const float* __restrict__ dw1, f16* __restrict__ w1x,
                 f16* __restrict__ w1h,
                 const float* __restrict__ tw1, const float* __restrict__ tb1,
                 const float* __restrict__ tw2, const float* __restrict__ tb2,
                 const float* __restrict__ db1, float* __restrict__ tv,
                 f16* __restrict__ nzb, DiffParams P)
{
  __shared__ f16 hbuf[2][128];
  __shared__ float e[DM], te[DM];
  __shared__ f16 hc[16][264];
  const int blk = blockIdx.x, t = threadIdx.x;
  if (blk < 16) {
    const int b = blk >> 1, nh = blk & 1;
    gi_gemm_chunks<3>(b, nh, t, xh96, Wc, cbc, gi, nullptr, &flags[F3 + b]);
  } else if (blk < 24) {
    const int b = blk - 16;
    scan_body<false, true, true, true>(b, t, gi, whh0h, bhh0,
                                       nullptr, h0h, hbuf,
                                       &flags[F0 + b], &flags[F3 + b]);
  } else if (blk < 40) {
    const int g = blk - 24, b = g >> 1, nh = g & 1;
    gi_gemm_chunks<8>(b, nh, t, h0h, wih1h, cb1, gi, &flags[F0 + b], &flags[F1 + b]);
  } else if (blk < 48) {
    const int b = blk - 40;
    scan_body<true, false, true, true>(b, t, gi, whh1h, bhh1,
                                       hA, nullptr, hbuf,
                                       &flags[F2 + b], &flags[F1 + b]);
  } else if (blk < 112) {
    // pack den_w2 fragment-order fp8 (grid-stride, 64 blocks over 512*512)
    for (int i = (blk - 48)*256 + t; i < 512*512; i += 64*256) {
      int j = i & 7;
      int lane = (i >> 3) & 63;
      int tk = i >> 9;
      int tt = tk >> 4, kt = tk & 15;
      int row = tt*16 + (lane & 15);
      int col = kt*32 + (lane >> 4)*8 + j;
      w2p[i] = f32_to_e4m3(dw2[row*512 + col]);
    }
  } else if (blk < 128) {
    for (int i = (blk - 112)*256 + t; i < OUTD*HH2; i += 16*256) w3h[i] = (f16)dw3[i];
  } else if (blk < 184) {
    // den_w1 [512][608] -> W1x [512][96], W1h [512][256]; publish w1done
    for (int i = (blk - 128)*256 + t; i < 512*96 + 512*256; i += 56*256) {
      if (i < 512*96) { int n = i/96, k = i%96; w1x[i] = (f16)dw1[n*608 + k]; }
      else { int jj = i - 512*96; int n = jj/256, k = jj%256; w1h[jj] = (f16)dw1[n*608 + 96 + k]; }
    }
    __syncthreads();
    if (t == 0)
      __hip_atomic_fetch_add(&flags[FW1], 1u, __ATOMIC_RELEASE, __HIP_MEMORY_SCOPE_AGENT);
  } else if (blk < 234) {
    // time embedding for step s: tv[s][512] = W1t @ t_emb(s) + den_b1
    const int s = blk - 184;
    float tn = (float)s / 49.f;
    { float v = tn * tw1[t] + tb1[t]; e[t] = siluf_(v); }
    __syncthreads();
    {
      float acc = tb2[t];
      const float* wr = tw2 + t*DM;
      #pragma unroll 8
      for (int k = 0; k < DM; k++) acc = fmaf(e[k], wr[k], acc);
      te[t] = acc;
    }
    __syncthreads();
    for (int n = t; n < HH2; n += 256) {
      float a2 = db1[n];
      const float* r = dw1 + n*608 + 352;
      #pragma unroll 8
      for (int k = 0; k < DM; k++) a2 = fmaf(te[k], r[k], a2);
      tv[s*HH2 + n] = a2;
    }
  } else if (blk < 298) {
    // LN + hpre GEMM: 64 blocks x 4 chunks (batch b, chunks 4*cg..4*cg+3)
    const int g = blk - 234, b = g >> 3, cg = g & 7;
    wait_flag(&flags[FW1], 56u);                       // w1h complete (56 split blocks)
    const int wave = t >> 6, lane = t & 63;
    float gl0=ln_g[lane], gl1=ln_g[lane+64], gl2=ln_g[lane+128], gl3=ln_g[lane+192];
    float bl0=ln_b[lane], bl1=ln_b[lane+64], bl2=ln_b[lane+128], bl3=ln_b[lane+192];
    for (int k4 = 0; k4 < 4; k4++) {
      const int c = cg*4 + k4;
      wait_flag(&flags[F2 + b], (uint32_t)((c+1)*CH));   // L1 hA rows ready
      const size_t R0 = (size_t)b*TT + c*CH;
      #pragma unroll
      for (int rr = 0; rr < 4; rr++) {
        int r = wave*4 + rr;
        const float* row = hA + (R0 + r)*DM;
        float v0=row[lane], v1=row[lane+64], v2=row[lane+128], v3=row[lane+192];
        float s = v0+v1+v2+v3;
        #pragma unroll
        for (int o2 = 32; o2; o2 >>= 1) s += __shfl_xor(s, o2, 64);
        float mu = s * (1.f/256.f);
        float d0=v0-mu, d1=v1-mu, d2=v2-mu, d3=v3-mu;
        float q = d0*d0+d1*d1+d2*d2+d3*d3;
        #pragma unroll
        for (int o2 = 32; o2; o2 >>= 1) q += __shfl_xor(q, o2, 64);
        float rs = rsqrtf(q*(1.f/256.f) + 1e-5f);
        hc[r][lane]     = (f16)(d0*rs*gl0 + bl0);
        hc[r][lane+64]  = (f16)(d1*rs*gl1 + bl1);
        hc[r][lane+128] = (f16)(d2*rs*gl2 + bl2);
        hc[r][lane+192] = (f16)(d3*rs*gl3 + bl3);
      }
      __syncthreads();
      const int l15 = lane & 15, quad = lane >> 4;
      const int kq = quad*8, rb = quad*4;
      f32x4 acc[8] = {};
      #pragma unroll
      for (int kt = 0; kt < 8; kt++) {
        f16x8 a = *(const f16x8*)&hc[l15][kt*32 + kq];
        #pragma unroll
        for (int nt = 0; nt < 8; nt++) {
          const f16* Bp = w1hh + (size_t)(wave*128 + nt*16 + l15)*DM + kq + kt*32;
          acc[nt] = __builtin_amdgcn_mfma_f32_16x16x32_f16(a, *(const f16x8*)Bp, acc[nt], 0,0,0);
        }
      }
      #pragma unroll
      for (int nt = 0; nt < 8; nt++) {
        int n = wave*128 + nt*16 + l15;
        #pragma unroll
        for (int r = 0; r < 4; r++)
          hpreh[(R0 + rb + r)*HH2 + n] = (f16)acc[nt][r];
      }
      __syncthreads();            // hc reused next chunk
    }
  } else {
    // noise table: 2048 blocks x 9792 contiguous elems (2048*9792 == NZTOT)
    long base = (long)(blk - 298) * 9792;
    long end  = base + 9792;
    while (base < end) {
      int s = (int)(base / NTOT);
      long segend = (long)(s + 1) * NTOT;
      if (segend > end) segend = end;
      uint32_t kk0 = (s < NSTEPS) ? P.k0[s] : P.xk0;
      uint32_t kk1 = (s < NSTEPS) ? P.k1[s] : P.xk1;
      long sbase = (long)s * NTOT;
      for (long ee = base + t; ee < segend; ee += 256)
        nzb[ee] = (f16)jax_normal_elem(kk0, kk1, (uint32_t)(ee - sbase));
      base = segend;
    }
  }
}

// ---------------- fused 50-step diffusion loop (round-10 best, unchanged) ----------------
#define YSTR  520   // f16 stride: 260 dw == 4 (mod 32) -> conflict-minimal b128
#define XHSTR 104   // f16 stride: 52 dw == 20 (mod 32)
#define W3STR 520

__device__ __forceinline__ int y1p_swz(int g) {
  return ((g >> 2) & 7) | ((g & 3) << 3) | (g & 32);
}

__global__ __launch_bounds__(1024)
void k_diff(const f16* __restrict__ w1x,   // [512][96]
            const unsigned char* __restrict__ w2p, // fragment-packed fp8 [512*512]
            const f16* __restrict__ w3h,   // [96][512]
            const f16* __restrict__ hpreh, // [4096][512]
            const float* __restrict__ tv,  // [50][512]
            const float* __restrict__ db2, // [512]
            const float* __restrict__ db3, // [96]
            const f16* __restrict__ nzb,   // [51][4096][96] precomputed noise
            float* __restrict__ out,
            DiffParams P)
{
  __shared__ unsigned char y1p_l[16*512]; // 8 KB: y1 fp8 A-frags, granule-swizzled
  __shared__ f16 y2_l[16*YSTR];     // 16.6 KB
  __shared__ f16 xh_l[16*XHSTR];    // 3.3 KB, x in A-layout
  __shared__ f16 w3_l[96*W3STR];    // 97.5 KB, step-invariant

  const int t = threadIdx.x;
  const int lane = t & 63;
  const int wave = t >> 6;          // 0..15
  const int quad = lane >> 4;
  const int l15 = lane & 15;
  const int m0 = blockIdx.x * 16;
  const int n0w = wave * 32;        // Y1/Y2: 16 waves x 32 cols (2 tiles)

  const int t0 = 2*wave, t1 = 2*wave + 1;   // this wave's two n-tiles
  const int lsw8 = y1p_swz(lane) << 3;      // consumer granule offset (bytes)

  // ---- preload step-invariant w2 B-fragments (spill to L2 scratch; reload coalesced)
  long w2f0[16], w2f1[16];
  {
    const unsigned char* p0 = w2p + (((size_t)(t0*16)*64 + lane) << 3);
    const unsigned char* p1 = w2p + (((size_t)(t1*16)*64 + lane) << 3);
    #pragma unroll
    for (int kt = 0; kt < 16; kt++) {
      w2f0[kt] = *(const long*)(p0 + kt*512);
      w2f1[kt] = *(const long*)(p1 + kt*512);
    }
  }
  // ---- preload this lane's hp epilogue values (8 regs, direct from global)
  float hpr[2][4];
  #pragma unroll
  for (int nt = 0; nt < 2; nt++)
    #pragma unroll
    for (int r = 0; r < 4; r++)
      hpr[nt][r] = (float)hpreh[(long)(m0 + quad*4 + r)*HH2 + n0w + nt*16 + l15];
  // ---- hoist db2 biases (step-invariant)
  const float db2r0 = db2[n0w + l15];
  const float db2r1 = db2[n0w + 16 + l15];

  // ---- stage w3 into LDS once (96 rows x 64 vec8)
  #pragma unroll
  for (int i = 0; i < 6; i++) {
    int v = t + i*1024;             // 0..6143
    int row = v >> 6, c8 = v & 63;
    *((f16x8*)&w3_l[row*W3STR] + c8) = *((const f16x8*)(w3h + row*HH2) + c8);
  }

  // ---- x0 init from precomputed slot 50: waves 0..5 own x in registers
  const int neps = wave * 16 + l15;
  float xreg[4];
  if (wave < 6) {
    #pragma unroll
    for (int r = 0; r < 4; r++) {
      int ml = quad*4 + r;
      float v = (float)nzb[(size_t)NSTEPS*NTOT + (size_t)(m0 + ml)*OUTD + neps];
      xreg[r] = v;
      xh_l[ml*XHSTR + neps] = (f16)v;
    }
  }

  for (int s = NSTEPS-1; s >= 0; --s) {
    __syncthreads();                // xh ready (stages/x0 on first iter); y1p_l free
    // ---- issue this step's noise loads NOW (consumed 2 phases later in EPS)
    f16 nzr[4];
    if (wave < 6 && s > 0) {
      #pragma unroll
      for (int r = 0; r < 4; r++)
        nzr[r] = nzb[(size_t)s*NTOT + (size_t)(m0 + quad*4 + r)*OUTD + neps];
    }
    // ---- Y1: K=96, 6 MFMA/wave (f16)
    {
      f32x4 acc[2] = {};
      #pragma unroll
      for (int kt = 0; kt < 3; kt++) {
        f16x8 a = *(const f16x8*)&xh_l[l15*XHSTR + kt*32 + quad*8];
        f16x8 b0 = *(const f16x8*)&w1x[(n0w + l15)*96 + kt*32 + quad*8];
        f16x8 b1 = *(const f16x8*)&w1x[(n0w + 16 + l15)*96 + kt*32 + quad*8];
        acc[0] = __builtin_amdgcn_mfma_f32_16x16x32_f16(a, b0, acc[0], 0,0,0);
        acc[1] = __builtin_amdgcn_mfma_f32_16x16x32_f16(a, b1, acc[1], 0,0,0);
      }
      // y1[ml][n] -> packed frag at swizzled granule: logical G = ml|lp, physical swz(G)
      #pragma unroll
      for (int nt = 0; nt < 2; nt++) {
        int n = n0w + nt*16 + l15;
        float tvv = tv[s*HH2 + n];
        int lp = ((nt*2 + (l15>>3)) << 4);
        int jp = l15 & 7;
        #pragma unroll
        for (int r = 0; r < 4; r++) {
          float v = (nt ? acc[1][r] : acc[0][r]) + hpr[nt][r] + tvv;
          int ml = quad*4 + r;
          y1p_l[wave*512 + (y1p_swz(ml | lp) << 3) + jp] = f32_to_e4m3(siluf_(v));
        }
      }
    }
    lds_barrier();                  // y1 complete (LDS-only dependency)
    // ---- Y2: K=512, 32 fp8-MFMA/wave
    {
      f32x4 acc2[2] = {};
      #pragma unroll
      for (int kt = 0; kt < 16; kt++) {
        long a  = *(const long*)(y1p_l + kt*512 + lsw8);
        acc2[0] = __builtin_amdgcn_mfma_f32_16x16x32_fp8_fp8(a, w2f0[kt], acc2[0], 0,0,0);
        acc2[1] = __builtin_amdgcn_mfma_f32_16x16x32_fp8_fp8(a, w2f1[kt], acc2[1], 0,0,0);
      }
      #pragma unroll
      for (int nt = 0; nt < 2; nt++) {
        int n = n0w + nt*16 + l15;
        float bb = nt ? db2r1 : db2r0;
        #pragma unroll
        for (int r = 0; r < 4; r++) {
          int ml = quad*4 + r;
          y2_l[ml*YSTR + n] = (f16)siluf_((nt ? acc2[1][r] : acc2[0][r]) + bb);
        }
      }
    }
    lds_barrier();                  // y2 complete (LDS-only dependency)
    // ---- EPS + x-update (waves 0-5); waves 6-15 idle to the top barrier
    if (wave < 6) {
      f32x4 acc3 = {};
      #pragma unroll 8
      for (int kt = 0; kt < 16; kt++) {
        f16x8 a = *(const f16x8*)&y2_l[l15*YSTR + kt*32 + quad*8];
        f16x8 b = *(const f16x8*)&w3_l[(wave*16 + l15)*W3STR + kt*32 + quad*8];
        acc3 = __builtin_amdgcn_mfma_f32_16x16x32_f16(a, b, acc3, 0,0,0);
      }
      float sra = P.sra[s], coeff = P.coeff[s], sb = P.sb[s];
      float b3 = db3[neps];
      #pragma unroll
      for (int r = 0; r < 4; r++) {
        int ml = quad*4 + r;
        float eps = acc3[r] + b3;
        float mean = sra * (xreg[r] - coeff * eps);
        float xn = mean;
        if (s > 0) xn = mean + sb * (float)nzr[r];
        xreg[r] = xn;
        xh_l[ml*XHSTR + neps] = (f16)xn;
      }
    }
  }
  // ---- output from registers: [...,:64] then [...,64:96]
  if (wave < 6) {
    #pragma unroll
    for (int r = 0; r < 4; r++) {
      long m = m0 + quad*4 + r;
      if (neps < 64) out[m*64 + neps] = xreg[r];
      else out[(long)MM*64 + m*32 + (neps - 64)] = xreg[r];
    }
  }
}

// ---------------- host ----------------
extern "C" void kernel_launch(void* const* d_in, const int* in_sizes, int n_in,
                              void* d_out, int out_size, void* d_ws, size_t ws_size,
                              hipStream_t stream)
{
  (void)in_sizes; (void)n_in; (void)out_size; (void)ws_size;
  const float* z_seq = (const float*)d_in[0];
  const float* o_seq = (const float*)d_in[1];
  const float* in_w  = (const float*)d_in[2];
  const float* in_b  = (const float*)d_in[3];
  const float* wih0  = (const float*)d_in[4];
  const float* whh0  = (const float*)d_in[5];
  const float* bih0  = (const float*)d_in[6];
  const float* bhh0  = (const float*)d_in[7];
  const float* wih1  = (const float*)d_in[8];
  const float* whh1  = (const float*)d_in[9];
  const float* bih1  = (const float*)d_in[10];
  const float* bhh1  = (const float*)d_in[11];
  const float* ln_g  = (const float*)d_in[12];
  const float* ln_b  = (const float*)d_in[13];
  const float* tw1   = (const float*)d_in[14];
  const float* tb1   = (const float*)d_in[15];
  const float* tw2   = (const float*)d_in[16];
  const float* tb2   = (const float*)d_in[17];
  const float* dw1   = (const float*)d_in[18];
  const float* db1   = (const float*)d_in[19];
  const float* dw2   = (const float*)d_in[20];
  const float* db2   = (const float*)d_in[21];
  const float* dw3   = (const float*)d_in[22];
  const float* db3   = (const float*)d_in[23];

  // workspace carve-up
  char* base = (char*)d_ws;
  size_t off = 0;
  auto alloc = [&](size_t bytes) -> void* {
    void* p = base + off;
    off = (off + bytes + 255) & ~(size_t)255;
    return p;
  };
  float* gi     = (float*)alloc((size_t)MM*G3*4);   // gi0; gi1 aliases (flag-ordered)
  float* hA     = (float*)alloc((size_t)MM*DM*4);
  f16*   hAh    = (f16*)  alloc((size_t)MM*DM*2);   // L0 h0 output
  f16*   hpreh  = (f16*)  alloc((size_t)MM*HH2*2);
  float* tv     = (float*)alloc((size_t)NSTEPS*HH2*4);
  f16*   whh0h  = (f16*)  alloc((size_t)G3*DM*2);
  f16*   wih1h  = (f16*)  alloc((size_t)G3*DM*2);
  f16*   whh1h  = (f16*)  alloc((size_t)G3*DM*2);
  f16*   w1xh   = (f16*)  alloc((size_t)HH2*96*2);
  f16*   w1hh   = (f16*)  alloc((size_t)HH2*DM*2);
  unsigned char* w2p = (unsigned char*)alloc((size_t)HH2*HH2);
  f16*   w3h    = (f16*)  alloc((size_t)OUTD*HH2*2);
  f16*   xh96   = (f16*)  alloc((size_t)MM*OUTD*2);
  f16*   Wc     = (f16*)  alloc((size_t)G3*OUTD*2);
  float* cbc    = (float*)alloc((size_t)G3*4);
  float* cb1    = (float*)alloc((size_t)G3*4);
  uint32_t* flags = (uint32_t*)alloc(256);
  f16*   nzb    = (f16*)  alloc((size_t)NZTOT*2);   // 40.1 MB noise table

  // host-side diffusion schedule + keys
  DiffParams P;
  {
    float ab = 1.f;
    float delta = (0.02f - 1e-4f) / 49.f;
    for (int i = 0; i < NSTEPS; i++) {
      float bt = 1e-4f + delta * (float)i;
      float al = 1.f - bt;
      ab *= al;
      P.sra[i]   = sqrtf(1.f / al);
      P.coeff[i] = bt / sqrtf(1.f - ab);
      P.sb[i]    = sqrtf(bt);
    }
    for (int s = 0; s < NSTEPS; s++) {
      uint32_t o0, o1;
      tf2x32(0u, 42u, 0u, (uint32_t)s, o0, o1);
      P.k0[s] = o0; P.k1[s] = o1;
    }
    uint32_t o0, o1;
    tf2x32(0u, 42u, 0u, (uint32_t)NSTEPS, o0, o1);
    P.xk0 = o0; P.xk1 = o1;
  }

  // 1. prep: weight f2h + folded inproj (Wc, cbc) + x pack + flag zero
  k_prep<<<676, 256, 0, stream>>>(
      z_seq, o_seq, in_w, in_b,
      wih0, whh0, whh0h, bih0, bhh0,
      wih1, wih1h, whh1, whh1h, bih1, bhh1, cb1,
      xh96, Wc, cbc, flags);
  // 2. FULL PIPELINE (single-poller waits, lower-ID wait invariant):
  //    gi0(K=96) || L0 || gi1 || L1 || LN+hpre, prep, noise table
  k_scan_pipe<<<298 + 2048, 256, 0, stream>>>(
      gi, whh0h, bhh0, hAh, xh96, Wc, cbc,
      wih1h, cb1, whh1h, bhh1, hA,
      ln_g, ln_b, w1hh, hpreh, flags,
      dw2, w2p, dw3, w3h, dw1, w1xh, w1hh,
      tw1, tb1, tw2, tb2, db1, tv, nzb, P);
  // 3. fused 50-step diffusion sampling (RNG-free)
  k_diff<<<256, 1024, 0, stream>>>(w1xh, w2p, w3h, hpreh, tv, db2, db3, nzb,
                                   (float*)d_out, P);
}